// Round 2
// baseline (379.262 us; speedup 1.0000x reference)
//
#include <hip/hip_runtime.h>

// 3-level db4 DWT, zero-padding mode, expressed as composite FIRs on x.
// child(t) = sum_j DEC[j] * parent(2t+1-j), parent zero-extended.
// Composition is exact because intermediate coeffs are 0 outside their valid
// range under the same formula (2*outsize-6 >= S at every level).

struct Weights {
    float w1h[8];    // level-1 high:  x[2s+1-j]
    float w2h[22];   // level-2 high:  x[4s+3-m], m=2j+k
    float w3h[50];   // level-3 high:  x[8s+7-m], m=4j+2k+l
    float w3l[50];   // level-3 low (approx)
};

constexpr Weights make_weights() {
    constexpr double LO[8] = {
        -0.010597401784997278,  0.032883011666982945,  0.030841381835986965,
        -0.18703481171888114,  -0.02798376941698385,   0.6308807679295904,
         0.7148465705525415,    0.23037781330885523};
    constexpr double HI[8] = {
        -0.23037781330885523,   0.7148465705525415,   -0.6308807679295904,
        -0.02798376941698385,   0.18703481171888114,   0.030841381835986965,
         0.032883011666982945, -0.010597401784997278};
    double a2h[22] = {}, a3h[50] = {}, a3l[50] = {};
    for (int j = 0; j < 8; ++j)
        for (int k = 0; k < 8; ++k)
            a2h[2 * j + k] += HI[j] * LO[k];
    for (int j = 0; j < 8; ++j)
        for (int k = 0; k < 8; ++k)
            for (int l = 0; l < 8; ++l) {
                a3h[4 * j + 2 * k + l] += HI[j] * LO[k] * LO[l];
                a3l[4 * j + 2 * k + l] += LO[j] * LO[k] * LO[l];
            }
    Weights W = {};
    for (int i = 0; i < 8; ++i)  W.w1h[i] = (float)HI[i];
    for (int i = 0; i < 22; ++i) W.w2h[i] = (float)a2h[i];
    for (int i = 0; i < 50; ++i) { W.w3h[i] = (float)a3h[i]; W.w3l[i] = (float)a3l[i]; }
    return W;
}

__device__ __constant__ Weights CW = make_weights();

__device__ __forceinline__ void fma4(float4& a, float c, const float4& v) {
    a.x = fmaf(c, v.x, a.x);
    a.y = fmaf(c, v.y, a.y);
    a.z = fmaf(c, v.z, a.z);
    a.w = fmaf(c, v.w, a.w);
}

// Grid: (512, 8) blocks of 256 threads. blockIdx.y = b. blockIdx.x -> s-chunk
// (8 rows of 128 floats = 32 float4 each). XCD-swizzled so each XCD owns a
// contiguous s range (~2 MB x window, L2-resident).
__global__ void __launch_bounds__(256) wavelet_fused_kernel(
        const float4* __restrict__ x, float4* __restrict__ out) {
    int c     = blockIdx.x;
    int chunk = ((c & 7) << 6) | (c >> 3);          // XCD k -> chunks [64k, 64k+64)
    int s     = chunk * 8 + (threadIdx.x >> 5);      // 0..4095
    int f     = threadIdx.x & 31;                    // float4 column
    int b     = blockIdx.y;

    const float4* xb = x + (long)b * 4096 * 32 + f;
    const float4 z = {0.f, 0.f, 0.f, 0.f};
    float4 h1 = z, h2 = z, h3 = z, l3 = z;

    if (s < 2051) {
        int r0 = 2 * s + 1;
#pragma unroll
        for (int j = 0; j < 8; ++j) {
            int r = r0 - j;
            float4 v = ((unsigned)r < 4096u) ? xb[r * 32] : z;
            fma4(h1, CW.w1h[j], v);
        }
    }
    if (s < 1029) {
        int r0 = 4 * s + 3;
#pragma unroll
        for (int m = 0; m < 22; ++m) {
            int r = r0 - m;
            float4 v = ((unsigned)r < 4096u) ? xb[r * 32] : z;
            fma4(h2, CW.w2h[m], v);
        }
    }
    if (s < 518) {
        int r0 = 8 * s + 7;
#pragma unroll
        for (int m = 0; m < 50; ++m) {
            int r = r0 - m;
            float4 v = ((unsigned)r < 4096u) ? xb[r * 32] : z;
            fma4(h3, CW.w3h[m], v);
            fma4(l3, CW.w3l[m], v);
        }
    }

    float4 hs;
    hs.x = h1.x + h2.x + h3.x;
    hs.y = h1.y + h2.y + h3.y;
    hs.z = h1.z + h2.z + h3.z;
    hs.w = h1.w + h2.w + h3.w;

    const long CH = 8L * 4096 * 32;
    long base = ((long)b * 4096 + s) * 32 + f;
    out[base]          = l3;   // c0 approx
    out[CH + base]     = h1;   // c1 d1
    out[2 * CH + base] = h2;   // c2 d2
    out[3 * CH + base] = h3;   // c3 d3
    out[4 * CH + base] = hs;   // c4 high_freq
    out[5 * CH + base] = l3;   // c5 low_freq
}

extern "C" void kernel_launch(void* const* d_in, const int* in_sizes, int n_in,
                              void* d_out, int out_size, void* d_ws, size_t ws_size,
                              hipStream_t stream) {
    const float4* x   = (const float4*)d_in[0];   // [8, 4096, 128] f32
    float4*       out = (float4*)d_out;           // [6, 8, 4096, 128] f32
    dim3 grid(512, 8);
    wavelet_fused_kernel<<<grid, 256, 0, stream>>>(x, out);
}

// Round 4
// 130.785 us; speedup vs baseline: 2.8999x; 2.8999x over previous
//
#include <hip/hip_runtime.h>

// 3-level db4 DWT, zero-padding mode, expressed as composite FIRs on x.
// child(t) = sum_j DEC[j] * parent(2t+1-j), parent zero-extended.
// Composition is exact because intermediate coeffs are 0 outside their valid
// range under the same formula (2*outsize-6 >= S at every level).

typedef float float4n __attribute__((ext_vector_type(4)));  // native vec for nt-store

struct Weights {
    float w1h[8];    // level-1 high:  x[2s+1-j]
    float w2h[22];   // level-2 high:  x[4s+3-m], m=2j+k
    float w3h[50];   // level-3 high:  x[8s+7-m], m=4j+2k+l
    float w3l[50];   // level-3 low (approx)
};

constexpr Weights make_weights() {
    constexpr double LO[8] = {
        -0.010597401784997278,  0.032883011666982945,  0.030841381835986965,
        -0.18703481171888114,  -0.02798376941698385,   0.6308807679295904,
         0.7148465705525415,    0.23037781330885523};
    constexpr double HI[8] = {
        -0.23037781330885523,   0.7148465705525415,   -0.6308807679295904,
        -0.02798376941698385,   0.18703481171888114,   0.030841381835986965,
         0.032883011666982945, -0.010597401784997278};
    double a2h[22] = {}, a3h[50] = {}, a3l[50] = {};
    for (int j = 0; j < 8; ++j)
        for (int k = 0; k < 8; ++k)
            a2h[2 * j + k] += HI[j] * LO[k];
    for (int j = 0; j < 8; ++j)
        for (int k = 0; k < 8; ++k)
            for (int l = 0; l < 8; ++l) {
                a3h[4 * j + 2 * k + l] += HI[j] * LO[k] * LO[l];
                a3l[4 * j + 2 * k + l] += LO[j] * LO[k] * LO[l];
            }
    Weights W = {};
    for (int i = 0; i < 8; ++i)  W.w1h[i] = (float)HI[i];
    for (int i = 0; i < 22; ++i) W.w2h[i] = (float)a2h[i];
    for (int i = 0; i < 50; ++i) { W.w3h[i] = (float)a3h[i]; W.w3l[i] = (float)a3l[i]; }
    return W;
}

__device__ __constant__ Weights CW = make_weights();

__device__ __forceinline__ void fma4(float4n& a, float c, const float4n& v) {
    a.x = fmaf(c, v.x, a.x);
    a.y = fmaf(c, v.y, a.y);
    a.z = fmaf(c, v.z, a.z);
    a.w = fmaf(c, v.w, a.w);
}

// Grid: (512, 8) blocks of 256 threads. blockIdx.y = b. blockIdx.x = s-chunk
// (8 rows of 128 floats = 32 float4 each). Identity chunk mapping: hardware
// round-robin dispatch spreads the heavy low-s chunks across all 8 XCDs
// (an explicit "locality" swizzle concentrated them on one XCD — R2 regression).
__global__ void __launch_bounds__(256) wavelet_fused_kernel(
        const float4n* __restrict__ x, float4n* __restrict__ out) {
    int chunk = blockIdx.x;
    int s     = chunk * 8 + (threadIdx.x >> 5);      // 0..4095
    int f     = threadIdx.x & 31;                    // float4 column
    int b     = blockIdx.y;

    const float4n* xb = x + (long)b * 4096 * 32 + f;
    const float4n z = {0.f, 0.f, 0.f, 0.f};
    float4n h1 = z, h2 = z, h3 = z, l3 = z;

    if (s < 2051) {
        int r0 = 2 * s + 1;
#pragma unroll
        for (int j = 0; j < 8; ++j) {
            int r = r0 - j;
            float4n v = ((unsigned)r < 4096u) ? xb[r * 32] : z;
            fma4(h1, CW.w1h[j], v);
        }
    }
    if (s < 1029) {
        int r0 = 4 * s + 3;
#pragma unroll
        for (int m = 0; m < 22; ++m) {
            int r = r0 - m;
            float4n v = ((unsigned)r < 4096u) ? xb[r * 32] : z;
            fma4(h2, CW.w2h[m], v);
        }
    }
    if (s < 518) {
        int r0 = 8 * s + 7;
#pragma unroll
        for (int m = 0; m < 50; ++m) {
            int r = r0 - m;
            float4n v = ((unsigned)r < 4096u) ? xb[r * 32] : z;
            fma4(h3, CW.w3h[m], v);
            fma4(l3, CW.w3l[m], v);
        }
    }

    float4n hs = h1 + h2 + h3;

    const long CH = 8L * 4096 * 32;
    long base = ((long)b * 4096 + s) * 32 + f;
    // Streaming outputs, never re-read: nontemporal keeps x L2-resident.
    __builtin_nontemporal_store(l3, &out[base]);            // c0 approx
    __builtin_nontemporal_store(h1, &out[CH + base]);       // c1 d1
    __builtin_nontemporal_store(h2, &out[2 * CH + base]);   // c2 d2
    __builtin_nontemporal_store(h3, &out[3 * CH + base]);   // c3 d3
    __builtin_nontemporal_store(hs, &out[4 * CH + base]);   // c4 high_freq
    __builtin_nontemporal_store(l3, &out[5 * CH + base]);   // c5 low_freq
}

extern "C" void kernel_launch(void* const* d_in, const int* in_sizes, int n_in,
                              void* d_out, int out_size, void* d_ws, size_t ws_size,
                              hipStream_t stream) {
    const float4n* x   = (const float4n*)d_in[0];   // [8, 4096, 128] f32
    float4n*       out = (float4n*)d_out;           // [6, 8, 4096, 128] f32
    dim3 grid(512, 8);
    wavelet_fused_kernel<<<grid, 256, 0, stream>>>(x, out);
}

// Round 5
// 121.437 us; speedup vs baseline: 3.1231x; 1.0770x over previous
//
#include <hip/hip_runtime.h>

// 3-level db4 DWT (zero-padding mode) as composite FIRs applied directly to x.
// child(t) = sum_j DEC[j]*parent(2t+1-j), zero-extended; composition exact.
// Thread coarsening x4 along s: one thread owns s=4q..4q+3, sharing the
// overlapping FIR windows (74/34/14 loads instead of 200/88/32).

typedef float float4n __attribute__((ext_vector_type(4)));

struct Weights {
    float w1h[8];    // level-1 high:  x[2s+1-j]
    float w2h[22];   // level-2 high:  x[4s+3-m], m=2j+k
    float w3h[50];   // level-3 high:  x[8s+7-m], m=4j+2k+l
    float w3l[50];   // level-3 low (approx)
};

constexpr Weights make_weights() {
    constexpr double LO[8] = {
        -0.010597401784997278,  0.032883011666982945,  0.030841381835986965,
        -0.18703481171888114,  -0.02798376941698385,   0.6308807679295904,
         0.7148465705525415,    0.23037781330885523};
    constexpr double HI[8] = {
        -0.23037781330885523,   0.7148465705525415,   -0.6308807679295904,
        -0.02798376941698385,   0.18703481171888114,   0.030841381835986965,
         0.032883011666982945, -0.010597401784997278};
    double a2h[22] = {}, a3h[50] = {}, a3l[50] = {};
    for (int j = 0; j < 8; ++j)
        for (int k = 0; k < 8; ++k)
            a2h[2 * j + k] += HI[j] * LO[k];
    for (int j = 0; j < 8; ++j)
        for (int k = 0; k < 8; ++k)
            for (int l = 0; l < 8; ++l) {
                a3h[4 * j + 2 * k + l] += HI[j] * LO[k] * LO[l];
                a3l[4 * j + 2 * k + l] += LO[j] * LO[k] * LO[l];
            }
    Weights W = {};
    for (int i = 0; i < 8; ++i)  W.w1h[i] = (float)HI[i];
    for (int i = 0; i < 22; ++i) W.w2h[i] = (float)a2h[i];
    for (int i = 0; i < 50; ++i) { W.w3h[i] = (float)a3h[i]; W.w3l[i] = (float)a3l[i]; }
    return W;
}

__device__ __constant__ Weights CW = make_weights();

__device__ __forceinline__ void fma4(float4n& a, float c, const float4n& v) {
    a.x = fmaf(c, v.x, a.x);
    a.y = fmaf(c, v.y, a.y);
    a.z = fmaf(c, v.z, a.z);
    a.w = fmaf(c, v.w, a.w);
}

// Grid: 1024 blocks x 256 threads. id = c*8 + b with b FAST so heavy blocks
// (c<=16, all b -> ids 0..135) land on 136 distinct CUs under round-robin.
// Thread: q = c*8 + (tid>>5) in [0,1024), owns output rows s = 4q..4q+3;
// f4 column = tid&31 (512 B rows, fully coalesced).
__global__ void __launch_bounds__(256) wavelet_fused_kernel(
        const float4n* __restrict__ x, float4n* __restrict__ out) {
    int id = blockIdx.x;
    int c  = id >> 3;
    int b  = id & 7;
    int q  = c * 8 + (threadIdx.x >> 5);   // 0..1023
    int f  = threadIdx.x & 31;

    const float4n* xb = x + (long)b * 4096 * 32 + f;
    const float4n z = {0.f, 0.f, 0.f, 0.f};
    float4n h1[4] = {z, z, z, z}, h2[4] = {z, z, z, z};
    float4n h3[4] = {z, z, z, z}, l3[4] = {z, z, z, z};

    // Level-3 (50-tap h+l, stride 8): rows [32q-42, 32q+31], 74 loads / 4 outputs
    if (q <= 129) {
        int rbase = 32 * q - 42;
#pragma unroll
        for (int rr = 0; rr < 74; ++rr) {
            int r = rbase + rr;
            float4n v = ((unsigned)r < 4096u) ? xb[r * 32] : z;
#pragma unroll
            for (int i = 0; i < 4; ++i) {
                int m = 8 * i + 49 - rr;           // compile-time per (rr,i)
                if (m >= 0 && m < 50) { fma4(h3[i], CW.w3h[m], v); fma4(l3[i], CW.w3l[m], v); }
            }
        }
    }
    // Level-2 (22-tap, stride 4): rows [16q-18, 16q+15], 34 loads / 4 outputs
    if (q <= 257) {
        int rbase = 16 * q - 18;
#pragma unroll
        for (int rr = 0; rr < 34; ++rr) {
            int r = rbase + rr;
            float4n v = ((unsigned)r < 4096u) ? xb[r * 32] : z;
#pragma unroll
            for (int i = 0; i < 4; ++i) {
                int m = 4 * i + 21 - rr;
                if (m >= 0 && m < 22) fma4(h2[i], CW.w2h[m], v);
            }
        }
    }
    // Level-1 (8-tap, stride 2): rows [8q-6, 8q+7], 14 loads / 4 outputs
    if (q <= 512) {
        int rbase = 8 * q - 6;
#pragma unroll
        for (int rr = 0; rr < 14; ++rr) {
            int r = rbase + rr;
            float4n v = ((unsigned)r < 4096u) ? xb[r * 32] : z;
#pragma unroll
            for (int i = 0; i < 4; ++i) {
                int m = 2 * i + 7 - rr;
                if (m >= 0 && m < 8) fma4(h1[i], CW.w1h[m], v);
            }
        }
    }

    const long CH = 8L * 4096 * 32;
#pragma unroll
    for (int i = 0; i < 4; ++i) {
        int s = 4 * q + i;
        if (s >= 518)  { h3[i] = z; l3[i] = z; }   // beyond coeff length: exact zero
        if (s >= 1029) h2[i] = z;
        if (s >= 2051) h1[i] = z;
        float4n hs = h1[i] + h2[i] + h3[i];
        long base = ((long)b * 4096 + s) * 32 + f;
        // Streaming outputs, never re-read: nontemporal keeps x L2-resident.
        __builtin_nontemporal_store(l3[i], &out[base]);            // c0 approx
        __builtin_nontemporal_store(h1[i], &out[CH + base]);       // c1 d1
        __builtin_nontemporal_store(h2[i], &out[2 * CH + base]);   // c2 d2
        __builtin_nontemporal_store(h3[i], &out[3 * CH + base]);   // c3 d3
        __builtin_nontemporal_store(hs,    &out[4 * CH + base]);   // c4 high_freq
        __builtin_nontemporal_store(l3[i], &out[5 * CH + base]);   // c5 low_freq
    }
}

extern "C" void kernel_launch(void* const* d_in, const int* in_sizes, int n_in,
                              void* d_out, int out_size, void* d_ws, size_t ws_size,
                              hipStream_t stream) {
    const float4n* x   = (const float4n*)d_in[0];   // [8, 4096, 128] f32
    float4n*       out = (float4n*)d_out;           // [6, 8, 4096, 128] f32
    wavelet_fused_kernel<<<1024, 256, 0, stream>>>(x, out);
}